// Round 2
// baseline (829.355 us; speedup 1.0000x reference)
//
#include <hip/hip_runtime.h>
#include <hip/hip_bf16.h>

#define H_ 224
#define W_ 224
#define C_ 64
#define F_ 256

typedef __attribute__((ext_vector_type(8))) short bf16x8;
typedef __attribute__((ext_vector_type(4))) float f32x4;

__device__ __forceinline__ unsigned short f2bf(float f) {
  union { float f; unsigned int u; } c; c.f = f;
  unsigned int u = c.u;
  return (unsigned short)((u + 0x7fffu + ((u >> 16) & 1u)) >> 16);
}

// Pre-pack U2 = Unp1 @ S into MFMA B-fragment layout [18][8][64][8] (N padded to 128),
// and Vt into [4][16][64][8] (K padded to 128).
__global__ __launch_bounds__(256) void prep_kernel(
    const float* __restrict__ Unp1, const float* __restrict__ S,
    const float* __restrict__ Vt,
    unsigned short* __restrict__ uFrag, unsigned short* __restrict__ vFrag) {
  int u = blockIdx.x * 256 + threadIdx.x;
  if (u < 576 * 128) {
    int k = u >> 7;       // 0..575
    int n = u & 127;      // 0..127
    float acc = 0.f;
    if (n < 100) {
      for (int q = 0; q < 100; ++q)
        acc += Unp1[k * 100 + q] * S[q * 100 + n];
    }
    int ks = k >> 5, kk = k & 31, g = kk >> 3, j = kk & 7;
    int nt = n >> 4, lm = n & 15;
    uFrag[(((ks * 8 + nt) * 64) + g * 16 + lm) * 8 + j] = f2bf(acc);
  } else {
    int u2 = u - 576 * 128;
    if (u2 < 4 * 16 * 64 * 8) {
      int j = u2 & 7;
      int lane = (u2 >> 3) & 63;
      int nt = (u2 >> 9) & 15;
      int ks = u2 >> 13;
      int k = ks * 32 + (lane >> 4) * 8 + j;
      int n = nt * 16 + (lane & 15);
      float v = (k < 100) ? Vt[k * 256 + n] : 0.f;
      vFrag[u2] = f2bf(v);
    }
  }
}

// Fused: per block, tile = 2 rows x 32 cols of one image.
// GEMM1: patches(64x576) @ U2(576x128) -> z1 (LDS, bf16)
// GEMM2: z1(64x128) @ Vt(128x256) + bias -> relu -> out
__global__ __launch_bounds__(256) void conv_kernel(
    const float* __restrict__ x,
    const unsigned short* __restrict__ uFrag,
    const unsigned short* __restrict__ vFrag,
    const float* __restrict__ bias,
    float* __restrict__ out) {
  __shared__ unsigned short xt[4 * 34 * 64];   // x halo tile, XOR-swizzled
  __shared__ unsigned short z1[64 * 128];      // intermediate, XOR-swizzled

  int bid = blockIdx.x;
  int tw = bid % 7;
  int th = (bid / 7) % 112;
  int bb = bid / (7 * 112);
  int h0 = th * 2, w0 = tw * 32;
  int tid = threadIdx.x;
  int lane = tid & 63, wid = tid >> 6;
  int wm = wid & 1, wn = wid >> 1;
  int g = lane >> 4, lm = lane & 15;

  // ---- stage x halo tile -> LDS bf16 (swizzled: chunk ^= row&7) ----
  const float* xb = x + (size_t)bb * (H_ * W_ * C_);
  #pragma unroll
  for (int it = 0; it < 5; ++it) {
    int i = tid + it * 256;
    if (i < 1088) {                       // 4*34*8 chunks of 8 elems
      int row34 = i >> 3, c8 = i & 7;
      int r = row34 / 34;
      int ww = row34 - r * 34;
      int h = h0 - 1 + r, w = w0 - 1 + ww;
      bf16x8 sv;
      if (h >= 0 && h < H_ && w >= 0 && w < W_) {
        const float* p = xb + ((size_t)(h * W_ + w)) * C_ + c8 * 8;
        float4 f0 = *(const float4*)p;
        float4 f1 = *(const float4*)(p + 4);
        sv[0] = (short)f2bf(f0.x); sv[1] = (short)f2bf(f0.y);
        sv[2] = (short)f2bf(f0.z); sv[3] = (short)f2bf(f0.w);
        sv[4] = (short)f2bf(f1.x); sv[5] = (short)f2bf(f1.y);
        sv[6] = (short)f2bf(f1.z); sv[7] = (short)f2bf(f1.w);
      } else {
        sv = (bf16x8){0, 0, 0, 0, 0, 0, 0, 0};
      }
      *(bf16x8*)&xt[row34 * 64 + ((c8 ^ (row34 & 7)) << 3)] = sv;
    }
  }
  __syncthreads();

  // ---- GEMM1 ----
  f32x4 acc1[2][4] = {};
  #pragma unroll
  for (int ks = 0; ks < 18; ++ks) {
    int cell = ks >> 1;
    int kh = cell / 3, kw = cell - kh * 3;
    int c0c = (ks & 1) * 4;               // chunk offset within row (units of 8 elems)
    bf16x8 a[2];
    #pragma unroll
    for (int t = 0; t < 2; ++t) {
      int mrow = (2 * wm + t) * 16 + lm;  // 0..63
      int dh = mrow >> 5, dw = mrow & 31;
      int row34 = (dh + kh) * 34 + dw + kw;
      int chunk = (c0c + g) ^ (row34 & 7);
      a[t] = *(const bf16x8*)&xt[row34 * 64 + chunk * 8];
    }
    #pragma unroll
    for (int j = 0; j < 4; ++j) {
      int nt = wn * 4 + j;
      bf16x8 bq = *(const bf16x8*)&uFrag[(((ks * 8 + nt) * 64) + lane) * 8];
      acc1[0][j] = __builtin_amdgcn_mfma_f32_16x16x32_bf16(a[0], bq, acc1[0][j], 0, 0, 0);
      acc1[1][j] = __builtin_amdgcn_mfma_f32_16x16x32_bf16(a[1], bq, acc1[1][j], 0, 0, 0);
    }
  }

  // ---- z1 -> LDS (bf16, swizzled) ----
  #pragma unroll
  for (int t = 0; t < 2; ++t) {
    #pragma unroll
    for (int j = 0; j < 4; ++j) {
      int col = (wn * 4 + j) * 16 + lm;
      #pragma unroll
      for (int i = 0; i < 4; ++i) {
        int row = (2 * wm + t) * 16 + g * 4 + i;
        z1[row * 128 + (((col >> 3) ^ (row & 7)) << 3) + (col & 7)] = f2bf(acc1[t][j][i]);
      }
    }
  }
  __syncthreads();

  // ---- GEMM2 ----
  f32x4 acc2[2][8] = {};
  #pragma unroll
  for (int ks = 0; ks < 4; ++ks) {
    bf16x8 a[2];
    #pragma unroll
    for (int t = 0; t < 2; ++t) {
      int row = (2 * wm + t) * 16 + lm;
      int chunk = (ks * 4 + g) ^ (row & 7);
      a[t] = *(const bf16x8*)&z1[row * 128 + chunk * 8];
    }
    #pragma unroll
    for (int j = 0; j < 8; ++j) {
      int nt = wn * 8 + j;
      bf16x8 bq = *(const bf16x8*)&vFrag[(((ks * 16 + nt) * 64) + lane) * 8];
      acc2[0][j] = __builtin_amdgcn_mfma_f32_16x16x32_bf16(a[0], bq, acc2[0][j], 0, 0, 0);
      acc2[1][j] = __builtin_amdgcn_mfma_f32_16x16x32_bf16(a[1], bq, acc2[1][j], 0, 0, 0);
    }
  }

  // ---- bias + relu + store ----
  #pragma unroll
  for (int t = 0; t < 2; ++t) {
    #pragma unroll
    for (int j = 0; j < 8; ++j) {
      int f = (wn * 8 + j) * 16 + lm;
      #pragma unroll
      for (int i = 0; i < 4; ++i) {
        int mrow = (2 * wm + t) * 16 + g * 4 + i;
        int dh = mrow >> 5, dw = mrow & 31;
        int h = h0 + dh, w = w0 + dw;
        size_t po = ((size_t)(h * W_ + w)) * F_ + f;
        float v = acc2[t][j][i] + bias[po];
        out[(size_t)bb * (H_ * W_ * F_) + po] = fmaxf(v, 0.f);
      }
    }
  }
}

extern "C" void kernel_launch(void* const* d_in, const int* in_sizes, int n_in,
                              void* d_out, int out_size, void* d_ws, size_t ws_size,
                              hipStream_t stream) {
  const float* x     = (const float*)d_in[0];
  const float* S     = (const float*)d_in[3];
  const float* Unp1  = (const float*)d_in[5];
  const float* Vtnp1 = (const float*)d_in[7];
  const float* bias  = (const float*)d_in[8];
  float* out = (float*)d_out;

  unsigned short* uFrag = (unsigned short*)d_ws;                    // 147456 B
  unsigned short* vFrag = (unsigned short*)((char*)d_ws + 18 * 8 * 64 * 8 * 2);  // 65536 B

  hipLaunchKernelGGL(prep_kernel, dim3(416), dim3(256), 0, stream,
                     Unp1, S, Vtnp1, uFrag, vFrag);
  hipLaunchKernelGGL(conv_kernel, dim3(8 * 112 * 7), dim3(256), 0, stream,
                     x, uFrag, vFrag, bias, out);
}

// Round 3
// 792.413 us; speedup vs baseline: 1.0466x; 1.0466x over previous
//
#include <hip/hip_runtime.h>
#include <hip/hip_bf16.h>

#define H_ 224
#define W_ 224
#define C_ 64
#define F_ 256

typedef __attribute__((ext_vector_type(8))) short bf16x8;
typedef __attribute__((ext_vector_type(4))) float f32x4;

__device__ __forceinline__ unsigned short f2bf(float f) {
  union { float f; unsigned int u; } c; c.f = f;
  unsigned int u = c.u;
  return (unsigned short)((u + 0x7fffu + ((u >> 16) & 1u)) >> 16);
}

// Pre-pack U2 = Unp1 @ S into MFMA B-fragment layout [18][8][64][8] (N padded to 128),
// and Vt into [4][16][64][8] (K padded to 128).
__global__ __launch_bounds__(256) void prep_kernel(
    const float* __restrict__ Unp1, const float* __restrict__ S,
    const float* __restrict__ Vt,
    unsigned short* __restrict__ uFrag, unsigned short* __restrict__ vFrag) {
  int u = blockIdx.x * 256 + threadIdx.x;
  if (u < 576 * 128) {
    int k = u >> 7;       // 0..575
    int n = u & 127;      // 0..127
    float acc = 0.f;
    if (n < 100) {
      for (int q = 0; q < 100; ++q)
        acc += Unp1[k * 100 + q] * S[q * 100 + n];
    }
    int ks = k >> 5, kk = k & 31, g = kk >> 3, j = kk & 7;
    int nt = n >> 4, lm = n & 15;
    uFrag[(((ks * 8 + nt) * 64) + g * 16 + lm) * 8 + j] = f2bf(acc);
  } else {
    int u2 = u - 576 * 128;
    if (u2 < 4 * 16 * 64 * 8) {
      int j = u2 & 7;
      int lane = (u2 >> 3) & 63;
      int nt = (u2 >> 9) & 15;
      int ks = u2 >> 13;
      int k = ks * 32 + (lane >> 4) * 8 + j;
      int n = nt * 16 + (lane & 15);
      float v = (k < 100) ? Vt[k * 256 + n] : 0.f;
      vFrag[u2] = f2bf(v);
    }
  }
}

// Fused: per block, tile = 2 rows x 32 cols of one image.
// GEMM1: patches(64x576) @ U2(576x128) -> z1 (LDS, bf16)
// GEMM2: z1(64x128) @ Vt(128x256) + bias -> relu -> out
__global__ __launch_bounds__(256, 4) void conv_kernel(
    const float* __restrict__ x,
    const unsigned short* __restrict__ uFrag,
    const unsigned short* __restrict__ vFrag,
    const float* __restrict__ bias,
    float* __restrict__ out) {
  __shared__ unsigned short xt[4 * 34 * 64];   // x halo tile, XOR-swizzled
  __shared__ unsigned short z1[64 * 128];      // intermediate, XOR-swizzled

  int bid = blockIdx.x;
  // bb FASTEST: 8 consecutive blocks = same tile across 8 images -> each image
  // pinned to one XCD (round-robin), bias/weight lines shared via L3.
  int bb = bid & 7;
  int t2 = bid >> 3;
  int tw = t2 % 7;
  int th = t2 / 7;
  int h0 = th * 2, w0 = tw * 32;
  int tid = threadIdx.x;
  int lane = tid & 63, wid = tid >> 6;
  int wm = wid & 1, wn = wid >> 1;
  int g = lane >> 4, lm = lane & 15;

  // ---- stage x halo tile -> LDS bf16 (swizzled: chunk ^= row&7) ----
  const float* xb = x + (size_t)bb * (H_ * W_ * C_);
  #pragma unroll
  for (int it = 0; it < 5; ++it) {
    int i = tid + it * 256;
    if (i < 1088) {                       // 4*34*8 chunks of 8 elems
      int row34 = i >> 3, c8 = i & 7;
      int r = row34 / 34;
      int ww = row34 - r * 34;
      int h = h0 - 1 + r, w = w0 - 1 + ww;
      bf16x8 sv;
      if (h >= 0 && h < H_ && w >= 0 && w < W_) {
        const float* p = xb + ((size_t)(h * W_ + w)) * C_ + c8 * 8;
        float4 f0 = *(const float4*)p;
        float4 f1 = *(const float4*)(p + 4);
        sv[0] = (short)f2bf(f0.x); sv[1] = (short)f2bf(f0.y);
        sv[2] = (short)f2bf(f0.z); sv[3] = (short)f2bf(f0.w);
        sv[4] = (short)f2bf(f1.x); sv[5] = (short)f2bf(f1.y);
        sv[6] = (short)f2bf(f1.z); sv[7] = (short)f2bf(f1.w);
      } else {
        sv = (bf16x8){0, 0, 0, 0, 0, 0, 0, 0};
      }
      *(bf16x8*)&xt[row34 * 64 + ((c8 ^ (row34 & 7)) << 3)] = sv;
    }
  }

  // per-thread output row offsets (h*W + w) for the 8 rows this thread owns
  int rowoff[2][4];
  #pragma unroll
  for (int t = 0; t < 2; ++t) {
    #pragma unroll
    for (int i = 0; i < 4; ++i) {
      int mrow = (2 * wm + t) * 16 + g * 4 + i;
      int dh = mrow >> 5, dw = mrow & 31;
      rowoff[t][i] = (h0 + dh) * W_ + (w0 + dw);
    }
  }

  __syncthreads();

  // ---- bias prefetch, first half (f = wn*128 + j*16 + lm, j=0..3) ----
  // Issued before GEMM1 so the 144 MFMAs hide the L3/HBM latency.
  float bv0[2][4][4];
  #pragma unroll
  for (int t = 0; t < 2; ++t)
    #pragma unroll
    for (int j = 0; j < 4; ++j)
      #pragma unroll
      for (int i = 0; i < 4; ++i)
        bv0[t][j][i] = bias[(size_t)rowoff[t][i] * F_ + (wn * 8 + j) * 16 + lm];

  // ---- GEMM1 ----
  f32x4 acc1[2][4] = {};
  #pragma unroll
  for (int ks = 0; ks < 18; ++ks) {
    int cell = ks >> 1;
    int kh = cell / 3, kw = cell - kh * 3;
    int c0c = (ks & 1) * 4;               // chunk offset within row (units of 8 elems)
    bf16x8 a[2];
    #pragma unroll
    for (int t = 0; t < 2; ++t) {
      int mrow = (2 * wm + t) * 16 + lm;  // 0..63
      int dh = mrow >> 5, dw = mrow & 31;
      int row34 = (dh + kh) * 34 + dw + kw;
      int chunk = (c0c + g) ^ (row34 & 7);
      a[t] = *(const bf16x8*)&xt[row34 * 64 + chunk * 8];
    }
    #pragma unroll
    for (int j = 0; j < 4; ++j) {
      int nt = wn * 4 + j;
      bf16x8 bq = *(const bf16x8*)&uFrag[(((ks * 8 + nt) * 64) + lane) * 8];
      acc1[0][j] = __builtin_amdgcn_mfma_f32_16x16x32_bf16(a[0], bq, acc1[0][j], 0, 0, 0);
      acc1[1][j] = __builtin_amdgcn_mfma_f32_16x16x32_bf16(a[1], bq, acc1[1][j], 0, 0, 0);
    }
  }

  // ---- z1 -> LDS (bf16, swizzled) ----
  #pragma unroll
  for (int t = 0; t < 2; ++t) {
    #pragma unroll
    for (int j = 0; j < 4; ++j) {
      int col = (wn * 4 + j) * 16 + lm;
      #pragma unroll
      for (int i = 0; i < 4; ++i) {
        int row = (2 * wm + t) * 16 + g * 4 + i;
        z1[row * 128 + (((col >> 3) ^ (row & 7)) << 3) + (col & 7)] = f2bf(acc1[t][j][i]);
      }
    }
  }
  __syncthreads();

  // ---- bias prefetch, second half (j=4..7); hidden under GEMM2 half 0 ----
  float bv1[2][4][4];
  #pragma unroll
  for (int t = 0; t < 2; ++t)
    #pragma unroll
    for (int j = 0; j < 4; ++j)
      #pragma unroll
      for (int i = 0; i < 4; ++i)
        bv1[t][j][i] = bias[(size_t)rowoff[t][i] * F_ + (wn * 8 + 4 + j) * 16 + lm];

  float* ob = out + (size_t)bb * (H_ * W_ * F_);

  // ---- GEMM2 half 0 (j = 0..3) ----
  {
    f32x4 acc2[2][4] = {};
    #pragma unroll
    for (int ks = 0; ks < 4; ++ks) {
      bf16x8 a[2];
      #pragma unroll
      for (int t = 0; t < 2; ++t) {
        int row = (2 * wm + t) * 16 + lm;
        int chunk = (ks * 4 + g) ^ (row & 7);
        a[t] = *(const bf16x8*)&z1[row * 128 + chunk * 8];
      }
      #pragma unroll
      for (int j = 0; j < 4; ++j) {
        int nt = wn * 8 + j;
        bf16x8 bq = *(const bf16x8*)&vFrag[(((ks * 16 + nt) * 64) + lane) * 8];
        acc2[0][j] = __builtin_amdgcn_mfma_f32_16x16x32_bf16(a[0], bq, acc2[0][j], 0, 0, 0);
        acc2[1][j] = __builtin_amdgcn_mfma_f32_16x16x32_bf16(a[1], bq, acc2[1][j], 0, 0, 0);
      }
    }
    #pragma unroll
    for (int t = 0; t < 2; ++t)
      #pragma unroll
      for (int j = 0; j < 4; ++j) {
        int f = (wn * 8 + j) * 16 + lm;
        #pragma unroll
        for (int i = 0; i < 4; ++i) {
          float v = fmaxf(acc2[t][j][i] + bv0[t][j][i], 0.f);
          __builtin_nontemporal_store(v, &ob[(size_t)rowoff[t][i] * F_ + f]);
        }
      }
  }

  // ---- GEMM2 half 1 (j = 4..7) ----
  {
    f32x4 acc2[2][4] = {};
    #pragma unroll
    for (int ks = 0; ks < 4; ++ks) {
      bf16x8 a[2];
      #pragma unroll
      for (int t = 0; t < 2; ++t) {
        int row = (2 * wm + t) * 16 + lm;
        int chunk = (ks * 4 + g) ^ (row & 7);
        a[t] = *(const bf16x8*)&z1[row * 128 + chunk * 8];
      }
      #pragma unroll
      for (int j = 0; j < 4; ++j) {
        int nt = wn * 8 + 4 + j;
        bf16x8 bq = *(const bf16x8*)&vFrag[(((ks * 16 + nt) * 64) + lane) * 8];
        acc2[0][j] = __builtin_amdgcn_mfma_f32_16x16x32_bf16(a[0], bq, acc2[0][j], 0, 0, 0);
        acc2[1][j] = __builtin_amdgcn_mfma_f32_16x16x32_bf16(a[1], bq, acc2[1][j], 0, 0, 0);
      }
    }
    #pragma unroll
    for (int t = 0; t < 2; ++t)
      #pragma unroll
      for (int j = 0; j < 4; ++j) {
        int f = (wn * 8 + 4 + j) * 16 + lm;
        #pragma unroll
        for (int i = 0; i < 4; ++i) {
          float v = fmaxf(acc2[t][j][i] + bv1[t][j][i], 0.f);
          __builtin_nontemporal_store(v, &ob[(size_t)rowoff[t][i] * F_ + f]);
        }
      }
  }
}

extern "C" void kernel_launch(void* const* d_in, const int* in_sizes, int n_in,
                              void* d_out, int out_size, void* d_ws, size_t ws_size,
                              hipStream_t stream) {
  const float* x     = (const float*)d_in[0];
  const float* S     = (const float*)d_in[3];
  const float* Unp1  = (const float*)d_in[5];
  const float* Vtnp1 = (const float*)d_in[7];
  const float* bias  = (const float*)d_in[8];
  float* out = (float*)d_out;

  unsigned short* uFrag = (unsigned short*)d_ws;                    // 147456 B
  unsigned short* vFrag = (unsigned short*)((char*)d_ws + 18 * 8 * 64 * 8 * 2);  // 65536 B

  hipLaunchKernelGGL(prep_kernel, dim3(416), dim3(256), 0, stream,
                     Unp1, S, Vtnp1, uFrag, vFrag);
  hipLaunchKernelGGL(conv_kernel, dim3(8 * 112 * 7), dim3(256), 0, stream,
                     x, uFrag, vFrag, bias, out);
}